// Round 7
// baseline (586.415 us; speedup 1.0000x reference)
//
#include <hip/hip_runtime.h>
#include <hip/hip_cooperative_groups.h>
#include <math.h>

namespace cg = cooperative_groups;

#define L_TOTAL 65536
#define D_DIM   256

typedef float vf4 __attribute__((ext_vector_type(4)));

// ================= fused cooperative kernel ================================
// 1024 blocks x 256 threads (4 blocks/CU co-resident exactly).
// Block b owns rows [64b, 64b+64); wave w owns rows [16w,16w+16);
// lane l owns cols [4l,4l+4). V is read ONCE and lives in v4[16] (64 VGPR).
// amdgpu_waves_per_eu(4,4): pin 4 waves/EU -> compiler may use up to 128
// VGPR. Round 3's failure was launch_bounds(256,4) alone: compiler chose
// 64 VGPR (8-wave heuristic) and spilled V to scratch (480 GB/s, +35 MB
// WRITE signature). K is consumed in two 8-row batches (32 VGPR live) via
// the round-6 verified row-merging butterfly (10 shuffles per 8 rows).
#define NB    1024      // blocks
#define RB    64        // rows per block
#define NSUP  32        // supers
#define SBLK  32        // blocks per super

__global__ __launch_bounds__(256)
__attribute__((amdgpu_waves_per_eu(4, 4)))
void kFused(
    const float* __restrict__ K, const float* __restrict__ V,
    const float* __restrict__ q,
    float* __restrict__ cm, float* __restrict__ cu,
    float* __restrict__ cw, float* __restrict__ T,
    float* __restrict__ out)
{
    const int t = threadIdx.x;
    const int b = blockIdx.x;
    const int S = b >> 5;          // super index
    const int jloc = b & 31;       // position within super
    const int r0 = b * RB;
    const int wave = t >> 6, lane = t & 63;

    __shared__ float s_lds[RB];
    __shared__ vf4  wbuf[4][64];           // phase1: partial-w; phase3: segments
    __shared__ float Lm[256], Lu[256];
    __shared__ float pmL[NB + 1], puL[NB + 1];
    __shared__ float sa[RB], se[RB], sri[RB];
    __shared__ vf4  seedL[64];
    __shared__ float asL[4];

    // ---------------- phase 1: block aggregates -----------------------------
    vf4 v4[16];
    {
        const vf4* Vp = reinterpret_cast<const vf4*>(V + (size_t)(r0 + wave * 16) * D_DIM) + lane;
        #pragma unroll
        for (int k = 0; k < 16; ++k) v4[k] = Vp[(size_t)k * (D_DIM / 4)];

        const vf4 q4 = *reinterpret_cast<const vf4*>(q + 4 * lane);
        const int b5 = (lane >> 5) & 1, b4 = (lane >> 4) & 1, b3 = (lane >> 3) & 1;
        const vf4* Kp = reinterpret_cast<const vf4*>(K + (size_t)(r0 + wave * 16) * D_DIM) + lane;

        #pragma unroll
        for (int batch = 0; batch < 2; ++batch) {
            // 8 K-rows in flight (32 VGPR), NT loads
            vf4 kv[8];
            #pragma unroll
            for (int k = 0; k < 8; ++k)
                kv[k] = __builtin_nontemporal_load(Kp + (size_t)(8 * batch + k) * (D_DIM / 4));
            float p[8];
            #pragma unroll
            for (int k = 0; k < 8; ++k)
                p[k] = kv[k].x * q4.x + kv[k].y * q4.y + kv[k].z * q4.z + kv[k].w * q4.w;

            // row-merging butterfly: level 1 (mask 32), rows pair (2i,2i+1)
            float tr[4];
            #pragma unroll
            for (int i = 0; i < 4; ++i) {
                const float a = b5 ? p[2 * i + 1] : p[2 * i];
                const float o = b5 ? p[2 * i]     : p[2 * i + 1];
                tr[i] = a + __shfl_xor(o, 32, 64);
            }
            float ur[2];
            #pragma unroll
            for (int i = 0; i < 2; ++i) {
                const float a = b4 ? tr[2 * i + 1] : tr[2 * i];
                const float o = b4 ? tr[2 * i]     : tr[2 * i + 1];
                ur[i] = a + __shfl_xor(o, 16, 64);
            }
            float vr;
            {
                const float a = b3 ? ur[1] : ur[0];
                const float o = b3 ? ur[0] : ur[1];
                vr = a + __shfl_xor(o, 8, 64);
            }
            vr += __shfl_xor(vr, 4, 64);
            vr += __shfl_xor(vr, 2, 64);
            vr += __shfl_xor(vr, 1, 64);
            if ((lane & 7) == 0)
                s_lds[wave * 16 + 8 * batch + (4 * b3 + 2 * b4 + b5)] = vr;
        }
    }
    __syncthreads();

    float m_b = -INFINITY;
    #pragma unroll
    for (int j = 0; j < RB; ++j) m_b = fmaxf(m_b, s_lds[j]);
    float u_b = 0.f;
    #pragma unroll
    for (int j = 0; j < RB; ++j) u_b += __expf(s_lds[j] - m_b);

    {
        vf4 pw = {0.f, 0.f, 0.f, 0.f};
        #pragma unroll
        for (int k = 0; k < 16; ++k)
            pw = pw + __expf(s_lds[wave * 16 + k] - m_b) * v4[k];
        wbuf[wave][lane] = pw;
    }
    __syncthreads();
    if (t < 64) {
        const vf4 w4 = (wbuf[0][t] + wbuf[1][t]) + (wbuf[2][t] + wbuf[3][t]);
        reinterpret_cast<vf4*>(cw)[(size_t)b * 64 + t] = w4;
    }
    if (t == 0) { cm[b] = m_b; cu[b] = u_b; }

    __threadfence();
    cg::this_grid().sync();

    // ---------------- phase 2a: redundant scalar (m,u) scan of 1024 ---------
    float am[4], au[4];
    float M = -INFINITY, U = 0.f;
    #pragma unroll
    for (int j = 0; j < 4; ++j) {
        am[j] = cm[4 * t + j]; au[j] = cu[4 * t + j];
        const float mm = fmaxf(M, am[j]);
        U = U * __expf(M - mm) + au[j] * __expf(am[j] - mm);
        M = mm;
    }
    Lm[t] = M; Lu[t] = U;
    float Mi = M, Ui = U;
    __syncthreads();
    for (int off = 1; off < 256; off <<= 1) {
        float m1 = 0.f, u1 = 0.f;
        const bool act = (t >= off);
        if (act) { m1 = Lm[t - off]; u1 = Lu[t - off]; }
        __syncthreads();
        if (act) {
            const float mm = fmaxf(m1, Mi);
            Ui = u1 * __expf(m1 - mm) + Ui * __expf(Mi - mm);
            Mi = mm;
            Lm[t] = Mi; Lu[t] = Ui;
        }
        __syncthreads();
    }
    float Me = (t == 0) ? -INFINITY : Lm[t - 1];
    float Ue = (t == 0) ? 0.f : Lu[t - 1];
    #pragma unroll
    for (int j = 0; j < 4; ++j) {
        pmL[4 * t + j] = Me; puL[4 * t + j] = Ue;
        const float mm = fmaxf(Me, am[j]);
        Ue = Ue * __expf(Me - mm) + au[j] * __expf(am[j] - mm);
        Me = mm;
    }
    if (t == 255) { pmL[NB] = Me; puL[NB] = Ue; }
    __syncthreads();

    // ---------------- phase 2b: blocks 0..31 compute super totals T ----------
    if (b < NSUP && t < 64) {
        vf4 PW = {0.f, 0.f, 0.f, 0.f};
        const vf4* cw4 = reinterpret_cast<const vf4*>(cw);
        #pragma unroll 8
        for (int j = 0; j < SBLK; ++j) {
            const int bb = b * SBLK + j;
            const float caj = __expf(pmL[bb] - pmL[bb + 1]);   // bb=0: exp(-inf)=0
            const float cbj = __expf(cm[bb] - pmL[bb + 1]);
            PW = PW * caj + cw4[(size_t)bb * 64 + t] * cbj;
        }
        reinterpret_cast<vf4*>(T)[(size_t)b * 64 + t] = PW;
    }
    __threadfence();
    cg::this_grid().sync();

    // ---------------- phase 3: prefix folds + row scan + output --------------
    if (wave == 0) {
        // 64-row shuffle scan (lanes = rows), seeded by (pmL[b], puL[b])
        const float pmc = pmL[b], puc = puL[b];
        const float s_val = s_lds[lane];
        float m = s_val, u = 1.0f;
        #pragma unroll
        for (int off = 1; off < 64; off <<= 1) {
            const float m1 = __shfl_up(m, off, 64);
            const float u1 = __shfl_up(u, off, 64);
            if (lane >= off) {
                const float mm = fmaxf(m1, m);
                u = u1 * __expf(m1 - mm) + u * __expf(m - mm);
                m = mm;
            }
        }
        const float m_row = fmaxf(pmc, m);
        const float u_row = puc * __expf(pmc - m_row) + u * __expf(m - m_row);
        const float mpr = __shfl_up(m_row, 1, 64);
        const float m_prev = (lane == 0) ? pmc : mpr;
        sa[lane]  = __expf(m_prev - m_row);    // row0 of block0: exp(-inf)=0
        se[lane]  = __expf(s_val - m_row);
        sri[lane] = 1.0f / u_row;
    } else if (wave == 1) {
        // exclusive vector prefix for this block, per column-quad = lane
        const float pmc = pmL[b];
        const float pmS = pmL[S * SBLK];
        const vf4* cw4 = reinterpret_cast<const vf4*>(cw);
        vf4 PW = {0.f, 0.f, 0.f, 0.f};
        for (int j = 0; j < jloc; ++j) {
            const int bb = S * SBLK + j;
            const float caj = __expf(pmL[bb] - pmL[bb + 1]);
            const float cbj = __expf(cm[bb] - pmL[bb + 1]);
            PW = PW * caj + cw4[(size_t)bb * 64 + lane] * cbj;
        }
        const vf4* T4 = reinterpret_cast<const vf4*>(T);
        vf4 SW = {0.f, 0.f, 0.f, 0.f};
        for (int Sp = 0; Sp < S; ++Sp) {
            const float g = __expf(pmL[Sp * SBLK] - pmL[Sp * SBLK + SBLK]); // S'=0: 0
            SW = SW * g + T4[(size_t)Sp * 64 + lane];
        }
        const float gf = (b == 0) ? 0.f : __expf(pmS - pmc);
        seedL[lane] = SW * gf + PW;
    }
    __syncthreads();

    // 4-segment vector recurrence: pass1 zero-init, combine, pass2 emit
    vf4 B = {0.f, 0.f, 0.f, 0.f};
    float A = 1.f;
    #pragma unroll
    for (int k = 0; k < 16; ++k) {
        const int j = wave * 16 + k;
        B = B * sa[j] + v4[k] * se[j];
        A *= sa[j];
    }
    wbuf[wave][lane] = B;
    if (lane == 0) asL[wave] = A;
    __syncthreads();

    vf4 W = seedL[lane];
    for (int p = 0; p < wave; ++p)
        W = W * asL[p] + wbuf[p][lane];

    float* Op = out + (size_t)(r0 + wave * 16) * D_DIM + 4 * lane;
    #pragma unroll
    for (int k = 0; k < 16; ++k) {
        const int j = wave * 16 + k;
        W = W * sa[j] + v4[k] * se[j];
        __builtin_nontemporal_store(W * sri[j],
                                    reinterpret_cast<vf4*>(Op + (size_t)k * D_DIM));
    }
}

// ================= fallback path (proven round-6 pipeline) =================
#define C_ROWS  32
#define N_CHUNK (L_TOTAL / C_ROWS)    // 2048
#define SUPER   32
#define N_SUPER (N_CHUNK / SUPER)     // 64

__global__ __launch_bounds__(256) void kA_aggregate(
    const float* __restrict__ K, const float* __restrict__ V,
    const float* __restrict__ q,
    float* __restrict__ s_g, float* __restrict__ cm,
    float* __restrict__ cu, float* __restrict__ cw)
{
    const int t = threadIdx.x;
    const int c = blockIdx.x;
    const int r0 = c * C_ROWS;
    const int wave = t >> 6, lane = t & 63;

    __shared__ float s_lds[C_ROWS];
    __shared__ vf4  pw_lds[4][64];

    const vf4* Kp = reinterpret_cast<const vf4*>(K + (size_t)(r0 + wave * 8) * D_DIM) + lane;
    vf4 kv[8];
    #pragma unroll
    for (int k = 0; k < 8; ++k)
        kv[k] = __builtin_nontemporal_load(Kp + (size_t)k * (D_DIM / 4));

    vf4 v4[8];
    const vf4* Vp = reinterpret_cast<const vf4*>(V + (size_t)(r0 + wave * 8) * D_DIM) + lane;
    #pragma unroll
    for (int k = 0; k < 8; ++k) v4[k] = Vp[(size_t)k * (D_DIM / 4)];

    const vf4 q4 = *reinterpret_cast<const vf4*>(q + 4 * lane);
    float p[8];
    #pragma unroll
    for (int k = 0; k < 8; ++k)
        p[k] = kv[k].x * q4.x + kv[k].y * q4.y + kv[k].z * q4.z + kv[k].w * q4.w;

    const int b5 = (lane >> 5) & 1, b4 = (lane >> 4) & 1, b3 = (lane >> 3) & 1;
    float tr[4];
    #pragma unroll
    for (int i = 0; i < 4; ++i) {
        const float a = b5 ? p[2 * i + 1] : p[2 * i];
        const float o = b5 ? p[2 * i]     : p[2 * i + 1];
        tr[i] = a + __shfl_xor(o, 32, 64);
    }
    float ur[2];
    #pragma unroll
    for (int i = 0; i < 2; ++i) {
        const float a = b4 ? tr[2 * i + 1] : tr[2 * i];
        const float o = b4 ? tr[2 * i]     : tr[2 * i + 1];
        ur[i] = a + __shfl_xor(o, 16, 64);
    }
    float vr;
    {
        const float a = b3 ? ur[1] : ur[0];
        const float o = b3 ? ur[0] : ur[1];
        vr = a + __shfl_xor(o, 8, 64);
    }
    vr += __shfl_xor(vr, 4, 64);
    vr += __shfl_xor(vr, 2, 64);
    vr += __shfl_xor(vr, 1, 64);
    if ((lane & 7) == 0)
        s_lds[wave * 8 + (4 * b3 + 2 * b4 + b5)] = vr;
    __syncthreads();

    if (t < C_ROWS) s_g[r0 + t] = s_lds[t];

    float m_c = -INFINITY;
    #pragma unroll
    for (int j = 0; j < C_ROWS; ++j) m_c = fmaxf(m_c, s_lds[j]);
    float u_c = 0.f;
    #pragma unroll
    for (int j = 0; j < C_ROWS; ++j) u_c += __expf(s_lds[j] - m_c);

    vf4 pw = {0.f, 0.f, 0.f, 0.f};
    #pragma unroll
    for (int k = 0; k < 8; ++k) {
        const float cf = __expf(s_lds[wave * 8 + k] - m_c);
        pw = pw + cf * v4[k];
    }
    pw_lds[wave][lane] = pw;
    __syncthreads();

    if (t < 64) {
        const vf4 w4 = (pw_lds[0][t] + pw_lds[1][t]) + (pw_lds[2][t] + pw_lds[3][t]);
        reinterpret_cast<vf4*>(cw + (size_t)c * D_DIM)[t] = w4;
    }
    if (t == 0) { cm[c] = m_c; cu[c] = u_c; }
}

__global__ __launch_bounds__(256) void kCB_scan(
    const float* __restrict__ cm, const float* __restrict__ cu,
    const float* __restrict__ cw,
    float* __restrict__ pm, float* __restrict__ pu,
    float* __restrict__ gsup,
    float* __restrict__ pwl, float* __restrict__ T)
{
    const int t = threadIdx.x;
    const int S = blockIdx.x;
    __shared__ float Lm[256], Lu[256];
    __shared__ float pmL[N_CHUNK + 1];
    __shared__ float ca[SUPER], cb[SUPER];

    float am[8], au[8];
    float M = -INFINITY, U = 0.f;
    #pragma unroll
    for (int j = 0; j < 8; ++j) {
        am[j] = cm[8 * t + j]; au[j] = cu[8 * t + j];
        const float mm = fmaxf(M, am[j]);
        U = U * __expf(M - mm) + au[j] * __expf(am[j] - mm);
        M = mm;
    }
    Lm[t] = M; Lu[t] = U;
    float Mi = M, Ui = U;
    __syncthreads();
    for (int off = 1; off < 256; off <<= 1) {
        float m1 = 0.f, u1 = 0.f;
        const bool act = (t >= off);
        if (act) { m1 = Lm[t - off]; u1 = Lu[t - off]; }
        __syncthreads();
        if (act) {
            const float mm = fmaxf(m1, Mi);
            Ui = u1 * __expf(m1 - mm) + Ui * __expf(Mi - mm);
            Mi = mm;
            Lm[t] = Mi; Lu[t] = Ui;
        }
        __syncthreads();
    }
    float Me = (t == 0) ? -INFINITY : Lm[t - 1];
    float Ue = (t == 0) ? 0.f : Lu[t - 1];
    #pragma unroll
    for (int j = 0; j < 8; ++j) {
        pmL[8 * t + j] = Me;
        if (S == 0) { pm[8 * t + j] = Me; pu[8 * t + j] = Ue; }
        const float mm = fmaxf(Me, am[j]);
        Ue = Ue * __expf(Me - mm) + au[j] * __expf(am[j] - mm);
        Me = mm;
    }
    if (t == 255) {
        pmL[N_CHUNK] = Me;
        if (S == 0) { pm[N_CHUNK] = Me; pu[N_CHUNK] = Ue; }
    }
    __syncthreads();

    float wv[SUPER];
    const float* cwp = cw + (size_t)S * SUPER * D_DIM + t;
    #pragma unroll
    for (int j = 0; j < SUPER; ++j) wv[j] = cwp[(size_t)j * D_DIM];

    if (t < SUPER) {
        const int c = S * SUPER + t;
        ca[t] = __expf(pmL[c] - pmL[c + 1]);
        cb[t] = __expf(cm[c] - pmL[c + 1]);
    }
    if (t == 0)
        gsup[S] = __expf(pmL[S * SUPER] - pmL[S * SUPER + SUPER]);
    __syncthreads();

    float PW = 0.f;
    float* pwlp = pwl + (size_t)S * SUPER * D_DIM + t;
    #pragma unroll
    for (int j = 0; j < SUPER; ++j) {
        pwlp[(size_t)j * D_DIM] = PW;
        PW = PW * ca[j] + wv[j] * cb[j];
    }
    T[(size_t)S * D_DIM + t] = PW;
}

__global__ __launch_bounds__(256) void kF_output(
    const float* __restrict__ V, const float* __restrict__ s_g,
    const float* __restrict__ pm, const float* __restrict__ pu,
    const float* __restrict__ pwl, const float* __restrict__ T,
    const float* __restrict__ gsup,
    float* __restrict__ out)
{
    const int t = threadIdx.x;
    const int c = blockIdx.x;
    const int S = c / SUPER;
    const int r0 = c * C_ROWS;
    const int wave = t >> 6, lane = t & 63;

    __shared__ float sa[C_ROWS], se[C_ROWS], sri[C_ROWS];
    __shared__ vf4 seedL[64];
    __shared__ vf4 seg[4][64];
    __shared__ float asL[4];
    __shared__ float GL[N_SUPER];

    vf4 v4[8];
    const vf4* Vp = reinterpret_cast<const vf4*>(V + (size_t)(r0 + wave * 8) * D_DIM) + lane;
    #pragma unroll
    for (int k = 0; k < 8; ++k) v4[k] = Vp[(size_t)k * (D_DIM / 4)];

    if (wave == 0) {
        const float pmc = pm[c];
        const float puc = pu[c];
        float s_val = -INFINITY;
        if (lane < C_ROWS) s_val = s_g[r0 + lane];
        float m = s_val, u = 1.0f;
        #pragma unroll
        for (int off = 1; off < C_ROWS; off <<= 1) {
            const float m1 = __shfl_up(m, off, 32);
            const float u1 = __shfl_up(u, off, 32);
            if ((lane & 31) >= off) {
                const float mm = fmaxf(m1, m);
                u = u1 * __expf(m1 - mm) + u * __expf(m - mm);
                m = mm;
            }
        }
        const float m_row = fmaxf(pmc, m);
        const float u_row = puc * __expf(pmc - m_row) + u * __expf(m - m_row);
        const float m_prev_raw = __shfl_up(m_row, 1, 32);
        const float m_prev = ((lane & 31) == 0) ? pmc : m_prev_raw;
        if (lane < C_ROWS) {
            sa[lane]  = __expf(m_prev - m_row);
            se[lane]  = __expf(s_val - m_row);
            sri[lane] = 1.0f / u_row;
        }
    } else if (wave == 1) {
        float h = (lane < S) ? gsup[lane] : 1.0f;
        #pragma unroll
        for (int off = 1; off < 64; off <<= 1) {
            const float tt = __shfl_down(h, off, 64);
            if (lane + off < 64) h *= tt;
        }
        float G = __shfl_down(h, 1, 64);
        if (lane == 63) G = 1.0f;
        GL[lane] = G;

        const float pmc = pm[c];
        const float pmS = pm[S * SUPER];
        vf4 SW = {0.f, 0.f, 0.f, 0.f};
        const vf4* T4 = reinterpret_cast<const vf4*>(T) + lane;
        #pragma unroll 8
        for (int Sp = 0; Sp < S; ++Sp)
            SW = SW + GL[Sp] * T4[(size_t)Sp * (D_DIM / 4)];
        const float gf = (c == 0) ? 0.f : __expf(pmS - pmc);
        const vf4 sp = reinterpret_cast<const vf4*>(pwl + (size_t)c * D_DIM)[lane];
        seedL[lane] = SW * gf + sp;
    }
    __syncthreads();

    vf4 B = {0.f, 0.f, 0.f, 0.f};
    float A = 1.f;
    #pragma unroll
    for (int k = 0; k < 8; ++k) {
        const int j = wave * 8 + k;
        B = B * sa[j] + v4[k] * se[j];
        A *= sa[j];
    }
    seg[wave][lane] = B;
    if (lane == 0) asL[wave] = A;
    __syncthreads();

    vf4 W = seedL[lane];
    for (int p = 0; p < wave; ++p)
        W = W * asL[p] + seg[p][lane];

    float* Op = out + (size_t)(r0 + wave * 8) * D_DIM + 4 * lane;
    #pragma unroll
    for (int k = 0; k < 8; ++k) {
        const int j = wave * 8 + k;
        W = W * sa[j] + v4[k] * se[j];
        __builtin_nontemporal_store(W * sri[j],
                                    reinterpret_cast<vf4*>(Op + (size_t)k * D_DIM));
    }
}

// ================= launch ==================================================
extern "C" void kernel_launch(void* const* d_in, const int* in_sizes, int n_in,
                              void* d_out, int out_size, void* d_ws, size_t ws_size,
                              hipStream_t stream) {
    const float* K = (const float*)d_in[0];
    const float* V = (const float*)d_in[1];
    const float* q = (const float*)d_in[2];
    float* out = (float*)d_out;
    float* ws = (float*)d_ws;

    // fused-path workspace
    float* cmF = ws;                                   // 1024
    float* cuF = cmF + NB;                             // 1024
    float* TF  = cuF + NB;                             // 32*256 = 8192
    float* cwF = TF + (size_t)NSUP * D_DIM;            // 1024*256
    float* fb  = cwF + (size_t)NB * D_DIM;             // fallback region base

    void* kargs[8];
    kargs[0] = (void*)&K;  kargs[1] = (void*)&V;   kargs[2] = (void*)&q;
    kargs[3] = (void*)&cmF; kargs[4] = (void*)&cuF; kargs[5] = (void*)&cwF;
    kargs[6] = (void*)&TF;  kargs[7] = (void*)&out;

    hipError_t err = hipLaunchCooperativeKernel(
        reinterpret_cast<const void*>(&kFused),
        dim3(NB), dim3(256), kargs, 0, stream);

    if (err != hipSuccess) {
        (void)hipGetLastError();   // clear sticky error; fall back
        float* s_g  = fb;                                  // 65536
        float* cm   = s_g + L_TOTAL;                       // 2048
        float* cu   = cm + N_CHUNK;                        // 2048
        float* pm   = cu + N_CHUNK;                        // 2049 (+pad)
        float* pu   = pm + (N_CHUNK + 16);                 // 2049 (+pad)
        float* gsup = pu + (N_CHUNK + 16);                 // 64 (+pad)
        float* cw   = gsup + 128;                          // 2048*256
        float* pwl  = cw + (size_t)N_CHUNK * D_DIM;        // 2048*256
        float* T    = pwl + (size_t)N_CHUNK * D_DIM;       // 64*256

        kA_aggregate<<<N_CHUNK, 256, 0, stream>>>(K, V, q, s_g, cm, cu, cw);
        kCB_scan<<<N_SUPER, 256, 0, stream>>>(cm, cu, cw, pm, pu, gsup, pwl, T);
        kF_output<<<N_CHUNK, 256, 0, stream>>>(V, s_g, pm, pu, pwl, T, gsup, out);
    }
}

// Round 8
// 183.840 us; speedup vs baseline: 3.1898x; 3.1898x over previous
//
#include <hip/hip_runtime.h>
#include <math.h>

#define L_TOTAL 65536
#define D_DIM   256

typedef float vf4 __attribute__((ext_vector_type(4)));

#define NB    1024      // blocks (4/CU x 256 CU — exactly resident)
#define RB    64        // rows per block
#define NSUP  32        // supers
#define SBLK  32        // blocks per super

// ---- tiny clear: zero the 4 grid-barrier words (ws is poisoned each iter) --
__global__ __launch_bounds__(64) void kClear(int* __restrict__ bar)
{
    if (threadIdx.x < 4) bar[threadIdx.x] = 0;
}

// ---- inline grid barrier: NO function call -> no ABI spill -----------------
__device__ __forceinline__ void grid_barrier(int* cnt, int* flag)
{
    __syncthreads();
    if (threadIdx.x == 0) {
        __threadfence();   // agent-scope release of this block's writes
        const int prev = __hip_atomic_fetch_add(cnt, 1, __ATOMIC_ACQ_REL,
                                                __HIP_MEMORY_SCOPE_AGENT);
        if (prev == NB - 1) {
            __hip_atomic_store(flag, 1, __ATOMIC_RELEASE, __HIP_MEMORY_SCOPE_AGENT);
        } else {
            while (__hip_atomic_load(flag, __ATOMIC_ACQUIRE,
                                     __HIP_MEMORY_SCOPE_AGENT) == 0)
                __builtin_amdgcn_s_sleep(16);
        }
    }
    __syncthreads();
}

// ================= fused kernel (V read once, lives in 64 VGPRs) ===========
// Block b owns rows [64b,64b+64); wave w rows [16w,16w+16); lane l cols [4l,4l+4).
// Rounds 3/7 failed because cg grid.sync() is a CALL -> fixed 64-VGPR ABI ->
// V spilled to scratch. Inline barrier removes the call; waves_per_eu(4,4)
// caps at 4 waves/EU (128 VGPR) so v4[16] stays in registers.
__global__
__attribute__((amdgpu_flat_work_group_size(256, 256), amdgpu_waves_per_eu(4, 4)))
void kFused(
    const float* __restrict__ K, const float* __restrict__ V,
    const float* __restrict__ q,
    float* __restrict__ cm, float* __restrict__ cu,
    float* __restrict__ cw, float* __restrict__ T,
    int* __restrict__ bar,
    float* __restrict__ out)
{
    const int t = threadIdx.x;
    const int b = blockIdx.x;
    const int S = b >> 5;          // super index
    const int jloc = b & 31;       // position within super
    const int r0 = b * RB;
    const int wave = t >> 6, lane = t & 63;

    __shared__ float s_lds[RB];
    __shared__ vf4  wbuf[4][64];
    __shared__ float Lm[256], Lu[256];
    __shared__ float pmL[NB + 1], puL[NB + 1];
    __shared__ float sa[RB], se[RB], sri[RB];
    __shared__ vf4  seedL[64];
    __shared__ float asL[4];

    // ---------------- phase 1: block aggregates -----------------------------
    vf4 v4[16];
    {
        const vf4* Vp = reinterpret_cast<const vf4*>(V + (size_t)(r0 + wave * 16) * D_DIM) + lane;
        #pragma unroll
        for (int k = 0; k < 16; ++k) v4[k] = Vp[(size_t)k * (D_DIM / 4)];

        const vf4 q4 = *reinterpret_cast<const vf4*>(q + 4 * lane);
        const int b5 = (lane >> 5) & 1, b4 = (lane >> 4) & 1, b3 = (lane >> 3) & 1;
        const vf4* Kp = reinterpret_cast<const vf4*>(K + (size_t)(r0 + wave * 16) * D_DIM) + lane;

        #pragma unroll
        for (int batch = 0; batch < 2; ++batch) {
            vf4 kv[8];
            #pragma unroll
            for (int k = 0; k < 8; ++k)
                kv[k] = __builtin_nontemporal_load(Kp + (size_t)(8 * batch + k) * (D_DIM / 4));
            float p[8];
            #pragma unroll
            for (int k = 0; k < 8; ++k)
                p[k] = kv[k].x * q4.x + kv[k].y * q4.y + kv[k].z * q4.z + kv[k].w * q4.w;

            float tr[4];
            #pragma unroll
            for (int i = 0; i < 4; ++i) {
                const float a = b5 ? p[2 * i + 1] : p[2 * i];
                const float o = b5 ? p[2 * i]     : p[2 * i + 1];
                tr[i] = a + __shfl_xor(o, 32, 64);
            }
            float ur[2];
            #pragma unroll
            for (int i = 0; i < 2; ++i) {
                const float a = b4 ? tr[2 * i + 1] : tr[2 * i];
                const float o = b4 ? tr[2 * i]     : tr[2 * i + 1];
                ur[i] = a + __shfl_xor(o, 16, 64);
            }
            float vr;
            {
                const float a = b3 ? ur[1] : ur[0];
                const float o = b3 ? ur[0] : ur[1];
                vr = a + __shfl_xor(o, 8, 64);
            }
            vr += __shfl_xor(vr, 4, 64);
            vr += __shfl_xor(vr, 2, 64);
            vr += __shfl_xor(vr, 1, 64);
            if ((lane & 7) == 0)
                s_lds[wave * 16 + 8 * batch + (4 * b3 + 2 * b4 + b5)] = vr;
        }
    }
    __syncthreads();

    float m_b = -INFINITY;
    #pragma unroll
    for (int j = 0; j < RB; ++j) m_b = fmaxf(m_b, s_lds[j]);
    float u_b = 0.f;
    #pragma unroll
    for (int j = 0; j < RB; ++j) u_b += __expf(s_lds[j] - m_b);

    {
        vf4 pw = {0.f, 0.f, 0.f, 0.f};
        #pragma unroll
        for (int k = 0; k < 16; ++k)
            pw = pw + __expf(s_lds[wave * 16 + k] - m_b) * v4[k];
        wbuf[wave][lane] = pw;
    }
    __syncthreads();
    if (t < 64) {
        const vf4 w4 = (wbuf[0][t] + wbuf[1][t]) + (wbuf[2][t] + wbuf[3][t]);
        reinterpret_cast<vf4*>(cw)[(size_t)b * 64 + t] = w4;
    }
    if (t == 0) { cm[b] = m_b; cu[b] = u_b; }

    grid_barrier(bar + 0, bar + 1);

    // ---------------- phase 2a: redundant scalar (m,u) scan of 1024 ---------
    float am[4], au[4];
    float M = -INFINITY, U = 0.f;
    #pragma unroll
    for (int j = 0; j < 4; ++j) {
        am[j] = cm[4 * t + j]; au[j] = cu[4 * t + j];
        const float mm = fmaxf(M, am[j]);
        U = U * __expf(M - mm) + au[j] * __expf(am[j] - mm);
        M = mm;
    }
    Lm[t] = M; Lu[t] = U;
    float Mi = M, Ui = U;
    __syncthreads();
    for (int off = 1; off < 256; off <<= 1) {
        float m1 = 0.f, u1 = 0.f;
        const bool act = (t >= off);
        if (act) { m1 = Lm[t - off]; u1 = Lu[t - off]; }
        __syncthreads();
        if (act) {
            const float mm = fmaxf(m1, Mi);
            Ui = u1 * __expf(m1 - mm) + Ui * __expf(Mi - mm);
            Mi = mm;
            Lm[t] = Mi; Lu[t] = Ui;
        }
        __syncthreads();
    }
    float Me = (t == 0) ? -INFINITY : Lm[t - 1];
    float Ue = (t == 0) ? 0.f : Lu[t - 1];
    #pragma unroll
    for (int j = 0; j < 4; ++j) {
        pmL[4 * t + j] = Me; puL[4 * t + j] = Ue;
        const float mm = fmaxf(Me, am[j]);
        Ue = Ue * __expf(Me - mm) + au[j] * __expf(am[j] - mm);
        Me = mm;
    }
    if (t == 255) { pmL[NB] = Me; puL[NB] = Ue; }
    __syncthreads();

    // ---------------- phase 2b: blocks 0..31 compute super totals ------------
    // Telescoped: coeff of cw[bb] in frame pmL[(Sb+1)*32] is e^{cm[bb]-pmL[end]}
    if (b < NSUP && t < 64) {
        const float fend = pmL[(b + 1) * SBLK];
        const vf4* cw4 = reinterpret_cast<const vf4*>(cw);
        vf4 PW = {0.f, 0.f, 0.f, 0.f};
        #pragma unroll 4
        for (int j = 0; j < SBLK; ++j) {
            const int bb = b * SBLK + j;
            PW = PW + __expf(cm[bb] - fend) * cw4[(size_t)bb * 64 + t];
        }
        reinterpret_cast<vf4*>(T)[(size_t)b * 64 + t] = PW;
    }

    grid_barrier(bar + 2, bar + 3);

    // ---------------- phase 3: seed + row scan + output ----------------------
    if (wave == 0) {
        const float pmc = pmL[b], puc = puL[b];
        const float s_val = s_lds[lane];
        float m = s_val, u = 1.0f;
        #pragma unroll
        for (int off = 1; off < 64; off <<= 1) {
            const float m1 = __shfl_up(m, off, 64);
            const float u1 = __shfl_up(u, off, 64);
            if (lane >= off) {
                const float mm = fmaxf(m1, m);
                u = u1 * __expf(m1 - mm) + u * __expf(m - mm);
                m = mm;
            }
        }
        const float m_row = fmaxf(pmc, m);
        const float u_row = puc * __expf(pmc - m_row) + u * __expf(m - m_row);
        const float mpr = __shfl_up(m_row, 1, 64);
        const float m_prev = (lane == 0) ? pmc : mpr;
        sa[lane]  = __expf(m_prev - m_row);    // row0 of block0: exp(-inf)=0
        se[lane]  = __expf(s_val - m_row);
        sri[lane] = 1.0f / u_row;
    } else if (wave == 1) {
        // Telescoped seed in frame pmL[b]: independent gathers, one exp each.
        // seed = sum_{Sp<S} e^{pmL[(Sp+1)*32]-pmL[b]} T[Sp]
        //      + sum_{j<jloc} e^{cm[bb]-pmL[b]} cw[bb]
        const float fb = pmL[b];
        vf4 SW = {0.f, 0.f, 0.f, 0.f};
        const vf4* T4  = reinterpret_cast<const vf4*>(T);
        const vf4* cw4 = reinterpret_cast<const vf4*>(cw);
        #pragma unroll 4
        for (int Sp = 0; Sp < S; ++Sp)
            SW = SW + __expf(pmL[(Sp + 1) * SBLK] - fb) * T4[(size_t)Sp * 64 + lane];
        #pragma unroll 4
        for (int j = 0; j < jloc; ++j) {
            const int bb = S * SBLK + j;
            SW = SW + __expf(cm[bb] - fb) * cw4[(size_t)bb * 64 + lane];
        }
        seedL[lane] = SW;
    }
    __syncthreads();

    vf4 B = {0.f, 0.f, 0.f, 0.f};
    float A = 1.f;
    #pragma unroll
    for (int k = 0; k < 16; ++k) {
        const int j = wave * 16 + k;
        B = B * sa[j] + v4[k] * se[j];
        A *= sa[j];
    }
    wbuf[wave][lane] = B;
    if (lane == 0) asL[wave] = A;
    __syncthreads();

    vf4 W = seedL[lane];
    for (int p = 0; p < wave; ++p)
        W = W * asL[p] + wbuf[p][lane];

    float* Op = out + (size_t)(r0 + wave * 16) * D_DIM + 4 * lane;
    #pragma unroll
    for (int k = 0; k < 16; ++k) {
        const int j = wave * 16 + k;
        W = W * sa[j] + v4[k] * se[j];
        __builtin_nontemporal_store(W * sri[j],
                                    reinterpret_cast<vf4*>(Op + (size_t)k * D_DIM));
    }
}

// ================= fallback path (proven round-6 pipeline) =================
#define C_ROWS  32
#define N_CHUNK (L_TOTAL / C_ROWS)    // 2048
#define SUPER   32
#define N_SUPER (N_CHUNK / SUPER)     // 64

__global__ __launch_bounds__(256) void kA_aggregate(
    const float* __restrict__ K, const float* __restrict__ V,
    const float* __restrict__ q,
    float* __restrict__ s_g, float* __restrict__ cm,
    float* __restrict__ cu, float* __restrict__ cw)
{
    const int t = threadIdx.x;
    const int c = blockIdx.x;
    const int r0 = c * C_ROWS;
    const int wave = t >> 6, lane = t & 63;

    __shared__ float s_lds[C_ROWS];
    __shared__ vf4  pw_lds[4][64];

    const vf4* Kp = reinterpret_cast<const vf4*>(K + (size_t)(r0 + wave * 8) * D_DIM) + lane;
    vf4 kv[8];
    #pragma unroll
    for (int k = 0; k < 8; ++k)
        kv[k] = __builtin_nontemporal_load(Kp + (size_t)k * (D_DIM / 4));

    vf4 v4[8];
    const vf4* Vp = reinterpret_cast<const vf4*>(V + (size_t)(r0 + wave * 8) * D_DIM) + lane;
    #pragma unroll
    for (int k = 0; k < 8; ++k) v4[k] = Vp[(size_t)k * (D_DIM / 4)];

    const vf4 q4 = *reinterpret_cast<const vf4*>(q + 4 * lane);
    float p[8];
    #pragma unroll
    for (int k = 0; k < 8; ++k)
        p[k] = kv[k].x * q4.x + kv[k].y * q4.y + kv[k].z * q4.z + kv[k].w * q4.w;

    const int b5 = (lane >> 5) & 1, b4 = (lane >> 4) & 1, b3 = (lane >> 3) & 1;
    float tr[4];
    #pragma unroll
    for (int i = 0; i < 4; ++i) {
        const float a = b5 ? p[2 * i + 1] : p[2 * i];
        const float o = b5 ? p[2 * i]     : p[2 * i + 1];
        tr[i] = a + __shfl_xor(o, 32, 64);
    }
    float ur[2];
    #pragma unroll
    for (int i = 0; i < 2; ++i) {
        const float a = b4 ? tr[2 * i + 1] : tr[2 * i];
        const float o = b4 ? tr[2 * i]     : tr[2 * i + 1];
        ur[i] = a + __shfl_xor(o, 16, 64);
    }
    float vr;
    {
        const float a = b3 ? ur[1] : ur[0];
        const float o = b3 ? ur[0] : ur[1];
        vr = a + __shfl_xor(o, 8, 64);
    }
    vr += __shfl_xor(vr, 4, 64);
    vr += __shfl_xor(vr, 2, 64);
    vr += __shfl_xor(vr, 1, 64);
    if ((lane & 7) == 0)
        s_lds[wave * 8 + (4 * b3 + 2 * b4 + b5)] = vr;
    __syncthreads();

    if (t < C_ROWS) s_g[r0 + t] = s_lds[t];

    float m_c = -INFINITY;
    #pragma unroll
    for (int j = 0; j < C_ROWS; ++j) m_c = fmaxf(m_c, s_lds[j]);
    float u_c = 0.f;
    #pragma unroll
    for (int j = 0; j < C_ROWS; ++j) u_c += __expf(s_lds[j] - m_c);

    vf4 pw = {0.f, 0.f, 0.f, 0.f};
    #pragma unroll
    for (int k = 0; k < 8; ++k) {
        const float cf = __expf(s_lds[wave * 8 + k] - m_c);
        pw = pw + cf * v4[k];
    }
    pw_lds[wave][lane] = pw;
    __syncthreads();

    if (t < 64) {
        const vf4 w4 = (pw_lds[0][t] + pw_lds[1][t]) + (pw_lds[2][t] + pw_lds[3][t]);
        reinterpret_cast<vf4*>(cw + (size_t)c * D_DIM)[t] = w4;
    }
    if (t == 0) { cm[c] = m_c; cu[c] = u_c; }
}

__global__ __launch_bounds__(256) void kCB_scan(
    const float* __restrict__ cm, const float* __restrict__ cu,
    const float* __restrict__ cw,
    float* __restrict__ pm, float* __restrict__ pu,
    float* __restrict__ gsup,
    float* __restrict__ pwl, float* __restrict__ T)
{
    const int t = threadIdx.x;
    const int S = blockIdx.x;
    __shared__ float Lm[256], Lu[256];
    __shared__ float pmL[N_CHUNK + 1];
    __shared__ float ca[SUPER], cb[SUPER];

    float am[8], au[8];
    float M = -INFINITY, U = 0.f;
    #pragma unroll
    for (int j = 0; j < 8; ++j) {
        am[j] = cm[8 * t + j]; au[j] = cu[8 * t + j];
        const float mm = fmaxf(M, am[j]);
        U = U * __expf(M - mm) + au[j] * __expf(am[j] - mm);
        M = mm;
    }
    Lm[t] = M; Lu[t] = U;
    float Mi = M, Ui = U;
    __syncthreads();
    for (int off = 1; off < 256; off <<= 1) {
        float m1 = 0.f, u1 = 0.f;
        const bool act = (t >= off);
        if (act) { m1 = Lm[t - off]; u1 = Lu[t - off]; }
        __syncthreads();
        if (act) {
            const float mm = fmaxf(m1, Mi);
            Ui = u1 * __expf(m1 - mm) + Ui * __expf(Mi - mm);
            Mi = mm;
            Lm[t] = Mi; Lu[t] = Ui;
        }
        __syncthreads();
    }
    float Me = (t == 0) ? -INFINITY : Lm[t - 1];
    float Ue = (t == 0) ? 0.f : Lu[t - 1];
    #pragma unroll
    for (int j = 0; j < 8; ++j) {
        pmL[8 * t + j] = Me;
        if (S == 0) { pm[8 * t + j] = Me; pu[8 * t + j] = Ue; }
        const float mm = fmaxf(Me, am[j]);
        Ue = Ue * __expf(Me - mm) + au[j] * __expf(am[j] - mm);
        Me = mm;
    }
    if (t == 255) {
        pmL[N_CHUNK] = Me;
        if (S == 0) { pm[N_CHUNK] = Me; pu[N_CHUNK] = Ue; }
    }
    __syncthreads();

    float wv[SUPER];
    const float* cwp = cw + (size_t)S * SUPER * D_DIM + t;
    #pragma unroll
    for (int j = 0; j < SUPER; ++j) wv[j] = cwp[(size_t)j * D_DIM];

    if (t < SUPER) {
        const int c = S * SUPER + t;
        ca[t] = __expf(pmL[c] - pmL[c + 1]);
        cb[t] = __expf(cm[c] - pmL[c + 1]);
    }
    if (t == 0)
        gsup[S] = __expf(pmL[S * SUPER] - pmL[S * SUPER + SUPER]);
    __syncthreads();

    float PW = 0.f;
    float* pwlp = pwl + (size_t)S * SUPER * D_DIM + t;
    #pragma unroll
    for (int j = 0; j < SUPER; ++j) {
        pwlp[(size_t)j * D_DIM] = PW;
        PW = PW * ca[j] + wv[j] * cb[j];
    }
    T[(size_t)S * D_DIM + t] = PW;
}

__global__ __launch_bounds__(256) void kF_output(
    const float* __restrict__ V, const float* __restrict__ s_g,
    const float* __restrict__ pm, const float* __restrict__ pu,
    const float* __restrict__ pwl, const float* __restrict__ T,
    const float* __restrict__ gsup,
    float* __restrict__ out)
{
    const int t = threadIdx.x;
    const int c = blockIdx.x;
    const int S = c / SUPER;
    const int r0 = c * C_ROWS;
    const int wave = t >> 6, lane = t & 63;

    __shared__ float sa[C_ROWS], se[C_ROWS], sri[C_ROWS];
    __shared__ vf4 seedL[64];
    __shared__ vf4 seg[4][64];
    __shared__ float asL[4];
    __shared__ float GL[N_SUPER];

    vf4 v4[8];
    const vf4* Vp = reinterpret_cast<const vf4*>(V + (size_t)(r0 + wave * 8) * D_DIM) + lane;
    #pragma unroll
    for (int k = 0; k < 8; ++k) v4[k] = Vp[(size_t)k * (D_DIM / 4)];

    if (wave == 0) {
        const float pmc = pm[c];
        const float puc = pu[c];
        float s_val = -INFINITY;
        if (lane < C_ROWS) s_val = s_g[r0 + lane];
        float m = s_val, u = 1.0f;
        #pragma unroll
        for (int off = 1; off < C_ROWS; off <<= 1) {
            const float m1 = __shfl_up(m, off, 32);
            const float u1 = __shfl_up(u, off, 32);
            if ((lane & 31) >= off) {
                const float mm = fmaxf(m1, m);
                u = u1 * __expf(m1 - mm) + u * __expf(m - mm);
                m = mm;
            }
        }
        const float m_row = fmaxf(pmc, m);
        const float u_row = puc * __expf(pmc - m_row) + u * __expf(m - m_row);
        const float m_prev_raw = __shfl_up(m_row, 1, 32);
        const float m_prev = ((lane & 31) == 0) ? pmc : m_prev_raw;
        if (lane < C_ROWS) {
            sa[lane]  = __expf(m_prev - m_row);
            se[lane]  = __expf(s_val - m_row);
            sri[lane] = 1.0f / u_row;
        }
    } else if (wave == 1) {
        float h = (lane < S) ? gsup[lane] : 1.0f;
        #pragma unroll
        for (int off = 1; off < 64; off <<= 1) {
            const float tt = __shfl_down(h, off, 64);
            if (lane + off < 64) h *= tt;
        }
        float G = __shfl_down(h, 1, 64);
        if (lane == 63) G = 1.0f;
        GL[lane] = G;

        const float pmc = pm[c];
        const float pmS = pm[S * SUPER];
        vf4 SW = {0.f, 0.f, 0.f, 0.f};
        const vf4* T4 = reinterpret_cast<const vf4*>(T) + lane;
        #pragma unroll 8
        for (int Sp = 0; Sp < S; ++Sp)
            SW = SW + GL[Sp] * T4[(size_t)Sp * (D_DIM / 4)];
        const float gf = (c == 0) ? 0.f : __expf(pmS - pmc);
        const vf4 sp = reinterpret_cast<const vf4*>(pwl + (size_t)c * D_DIM)[lane];
        seedL[lane] = SW * gf + sp;
    }
    __syncthreads();

    vf4 B = {0.f, 0.f, 0.f, 0.f};
    float A = 1.f;
    #pragma unroll
    for (int k = 0; k < 8; ++k) {
        const int j = wave * 8 + k;
        B = B * sa[j] + v4[k] * se[j];
        A *= sa[j];
    }
    seg[wave][lane] = B;
    if (lane == 0) asL[wave] = A;
    __syncthreads();

    vf4 W = seedL[lane];
    for (int p = 0; p < wave; ++p)
        W = W * asL[p] + seg[p][lane];

    float* Op = out + (size_t)(r0 + wave * 8) * D_DIM + 4 * lane;
    #pragma unroll
    for (int k = 0; k < 8; ++k) {
        const int j = wave * 8 + k;
        W = W * sa[j] + v4[k] * se[j];
        __builtin_nontemporal_store(W * sri[j],
                                    reinterpret_cast<vf4*>(Op + (size_t)k * D_DIM));
    }
}

// ================= launch ==================================================
extern "C" void kernel_launch(void* const* d_in, const int* in_sizes, int n_in,
                              void* d_out, int out_size, void* d_ws, size_t ws_size,
                              hipStream_t stream) {
    const float* K = (const float*)d_in[0];
    const float* V = (const float*)d_in[1];
    const float* q = (const float*)d_in[2];
    float* out = (float*)d_out;
    float* ws = (float*)d_ws;

    // residency guard: the inline grid barrier needs all 1024 blocks resident
    // (4 blocks/CU x 256 CU). Pure host-side query; cached.
    static int g_occ = -1;
    if (g_occ < 0) {
        int nb = 0;
        hipError_t e = hipOccupancyMaxActiveBlocksPerMultiprocessor(
            &nb, reinterpret_cast<const void*>(&kFused), 256, 0);
        g_occ = (e == hipSuccess) ? nb : 0;
        (void)hipGetLastError();
    }

    // fused-path workspace
    int*   bar = (int*)ws;                             // 4 barrier words (+pad)
    float* cmF = ws + 16;                              // 1024
    float* cuF = cmF + NB;                             // 1024
    float* TF  = cuF + NB;                             // 32*256
    float* cwF = TF + (size_t)NSUP * D_DIM;            // 1024*256
    float* fb  = cwF + (size_t)NB * D_DIM;             // fallback region base

    if (g_occ >= 4) {
        kClear<<<1, 64, 0, stream>>>(bar);
        kFused<<<NB, 256, 0, stream>>>(K, V, q, cmF, cuF, cwF, TF, bar, out);
    } else {
        float* s_g  = fb;                                  // 65536
        float* cm   = s_g + L_TOTAL;                       // 2048
        float* cu   = cm + N_CHUNK;                        // 2048
        float* pm   = cu + N_CHUNK;                        // 2049 (+pad)
        float* pu   = pm + (N_CHUNK + 16);                 // 2049 (+pad)
        float* gsup = pu + (N_CHUNK + 16);                 // 64 (+pad)
        float* cw   = gsup + 128;                          // 2048*256
        float* pwl  = cw + (size_t)N_CHUNK * D_DIM;        // 2048*256
        float* T    = pwl + (size_t)N_CHUNK * D_DIM;       // 64*256

        kA_aggregate<<<N_CHUNK, 256, 0, stream>>>(K, V, q, s_g, cm, cu, cw);
        kCB_scan<<<N_SUPER, 256, 0, stream>>>(cm, cu, cw, pm, pu, gsup, pwl, T);
        kF_output<<<N_CHUNK, 256, 0, stream>>>(V, s_g, pm, pu, pwl, T, gsup, out);
    }
}